// Round 7
// baseline (383.031 us; speedup 1.0000x reference)
//
#include <hip/hip_runtime.h>
#include <math.h>

#define N_NODES 50000
#define N_EDGES 200000
#define N_GRAPHS 1024
#define DIM 24
#define EF 8
#define EH 128
#define DD 576   // 24*24
#define HSTR 136 // hs row stride in f16: 128 + 8 pad (breaks stage-A write conflicts)

typedef __attribute__((ext_vector_type(8))) _Float16 f16x8;
typedef __attribute__((ext_vector_type(4))) _Float16 f16x4;
typedef __attribute__((ext_vector_type(2))) _Float16 f16x2;
typedef __attribute__((ext_vector_type(4))) float float4e;
typedef _Float16 f16;

// ---------- helpers ----------
static __device__ __forceinline__ float sigm(float x) { return 1.0f / (1.0f + expf(-x)); }

// ---------- deg (in-degree per node) ----------
__global__ void deg_kernel(const int* __restrict__ dst, int* __restrict__ deg) {
    int i = blockIdx.x * blockDim.x + threadIdx.x;
    if (i < N_EDGES) atomicAdd(&deg[dst[i]], 1);
}

// ---------- Bz: w2 (+b2) pre-swizzled f16 into exact MFMA b-fragment order ----------
// 97 k-steps of 32: step p = si*24+i covers k-window si*32..+32 of x-feature i;
// step 96 = bias block (A = x, B = b2 reshaped).
// Layout: Bz[p 97][nt 2][lane 64][kk 8] f16; lane = quad*16+l16,
// element = B[k32=quad*8+kk][n=nt*16+l16] (n>=24 -> 0). 198,656 B, L2-resident.
__global__ __launch_bounds__(256) void bz_kernel(const float* __restrict__ w2,
                                                 const float* __restrict__ b2,
                                                 f16* __restrict__ Bz) {
    int idx = blockIdx.x * 256 + threadIdx.x;
    if (idx >= 97 * 2 * 64 * 8) return;
    int kk = idx & 7, lane = (idx >> 3) & 63, nt = (idx >> 9) & 1, p = idx >> 10;
    int q = lane >> 4, l16 = lane & 15, n = nt * 16 + l16;
    float v = 0.0f;
    if (p < 96) {
        int si = p / 24, i = p % 24;
        int k = si * 32 + q * 8 + kk;
        if (n < 24) v = w2[(size_t)k * DD + i * 24 + n];
    } else {
        int i2 = q * 8 + kk;
        if (i2 < 24 && n < 24) v = b2[i2 * 24 + n];
    }
    Bz[idx] = (f16)v;
}

// ---------- fused NNConv: h-MLP + per-edge matvec as one z-GEMM, no W ----------
// grid 782, block 256 (4 waves, 256 edges).  Round-7 changes vs round 6:
//  * wave owns 64 edges (4 m-tiles) sharing each b-frag pair -> 8 MFMA per
//    2 b-loads: halves Bz L1-line-serve time (r6's dominant cost, ~31us/CU)
//    and halves total wave count (stage-A + loop VALU amortized 2x).
//  * depth-4 b-frag pipeline (32 VGPR, compile-time p&3 slots) covers ~200cyc
//    L2 latency at the lower occupancy (LDS 69.6KB -> 2 blocks/CU).
//  * __launch_bounds__(256,2): 256-VGPR budget so the ~170-reg working set
//    (acc 32 + x 48 + pipe 32 + h 16 + temps) is not compiler-sunk.
__global__ __launch_bounds__(256, 2) void conv_kernel(
    const float* __restrict__ x, const float* __restrict__ ea,
    const float* __restrict__ w1, const float* __restrict__ b1,
    const f16* __restrict__ Bz,
    const int* __restrict__ src, const int* __restrict__ dst,
    float* __restrict__ agg)
{
    __shared__ f16 hs[256 * HSTR];   // 69,632 B -> 2 blocks/CU

    const int t  = threadIdx.x;
    const int e0 = blockIdx.x * 256;

    const int lane = t & 63;
    const int wave = t >> 6;             // wave owns edges e0+wave*64 .. +64
    const int l16  = lane & 15;          // A row (edge) / B col / C col
    const int quad = lane >> 4;          // k sub-block / C row group
    const int ebase = e0 + wave * 64;

    // ---- x rows for 4 m-tiles -> f16 registers (issued first; L1 dedups quads) ----
    f16x2 xv[4][12];
    #pragma unroll
    for (int m = 0; m < 4; ++m) {
        int eg = ebase + m * 16 + l16; if (eg >= N_EDGES) eg = N_EDGES - 1;
        const float* xr = x + (size_t)src[eg] * DIM;
        #pragma unroll
        for (int j4 = 0; j4 < 6; ++j4) {
            float4 v = *(const float4*)(xr + j4 * 4);
            xv[m][j4 * 2]     = (f16x2){(f16)v.x, (f16)v.y};
            xv[m][j4 * 2 + 1] = (f16x2){(f16)v.z, (f16)v.w};
        }
    }

    // ---- prime depth-4 b-frag pipeline (independent of LDS; hides under stage A) ----
    const f16x8* bz = (const f16x8*)Bz + lane;
    f16x8 pb0[4], pb1[4];
    #pragma unroll
    for (int s = 0; s < 4; ++s) { pb0[s] = bz[s * 128]; pb1[s] = bz[s * 128 + 64]; }

    // ---- stage A: h = relu(ea@w1+b1) -> hs[edge][k]; thread = 4-k-slice x 32 edges ----
    {
        const int s5 = t & 31;           // k = s5*4 .. s5*4+3
        const int eb = (t >> 5) * 32;    // 32 edges starting here
        float wv[EF][4];
        #pragma unroll
        for (int j = 0; j < EF; ++j) {
            float4 v = *(const float4*)(w1 + j * EH + s5 * 4);
            wv[j][0] = v.x; wv[j][1] = v.y; wv[j][2] = v.z; wv[j][3] = v.w;
        }
        float4 bv = *(const float4*)(b1 + s5 * 4);
        const float bvv[4] = {bv.x, bv.y, bv.z, bv.w};
        #pragma unroll
        for (int e = 0; e < 32; ++e) {
            int eg = e0 + eb + e; if (eg >= N_EDGES) eg = N_EDGES - 1;  // clamp tail
            const float* ear = ea + (size_t)eg * EF;
            float4 a0 = *(const float4*)ear;
            float4 a1 = *(const float4*)(ear + 4);
            const float av[EF] = {a0.x, a0.y, a0.z, a0.w, a1.x, a1.y, a1.z, a1.w};
            float r[4] = {bvv[0], bvv[1], bvv[2], bvv[3]};
            #pragma unroll
            for (int j = 0; j < EF; ++j)
                #pragma unroll
                for (int c = 0; c < 4; ++c)
                    r[c] = fmaf(av[j], wv[j][c], r[c]);
            f16x4 hq = { (f16)fmaxf(r[0], 0.0f), (f16)fmaxf(r[1], 0.0f),
                         (f16)fmaxf(r[2], 0.0f), (f16)fmaxf(r[3], 0.0f) };
            *(f16x4*)&hs[(eb + e) * HSTR + s5 * 4] = hq;
        }
    }

    __syncthreads();

    float4e acc[4][2];
    #pragma unroll
    for (int m = 0; m < 4; ++m) {
        float4e z4 = {0.f, 0.f, 0.f, 0.f};
        acc[m][0] = z4; acc[m][1] = z4;
    }

    #pragma unroll
    for (int si = 0; si < 4; ++si) {
        union { f16x8 v; f16x2 h[4]; } hm[4];
        #pragma unroll
        for (int m = 0; m < 4; ++m)
            hm[m].v = *(const f16x8*)&hs[(wave * 64 + m * 16 + l16) * HSTR + si * 32 + quad * 8];
        #pragma unroll
        for (int i = 0; i < 24; ++i) {
            const int p = si * 24 + i;          // compile-time
            f16x8 b0 = pb0[p & 3], b1v = pb1[p & 3];
            if (p + 4 <= 96) {                  // prefetch 4 steps ahead into freed slot
                pb0[p & 3] = bz[(p + 4) * 128];
                pb1[p & 3] = bz[(p + 4) * 128 + 64];
            }
            #pragma unroll
            for (int m = 0; m < 4; ++m) {
                f16 xe = (i & 1) ? xv[m][i >> 1][1] : xv[m][i >> 1][0];
                f16x2 xx = {xe, xe};
                union { f16x8 v; f16x2 q[4]; } au;
                #pragma unroll
                for (int j = 0; j < 4; ++j) au.q[j] = hm[m].h[j] * xx;   // v_pk_mul_f16
                acc[m][0] = __builtin_amdgcn_mfma_f32_16x16x32_f16(au.v, b0,  acc[m][0], 0, 0, 0);
                acc[m][1] = __builtin_amdgcn_mfma_f32_16x16x32_f16(au.v, b1v, acc[m][1], 0, 0, 0);
            }
            if ((p % 12) == 11) __syncthreads();   // lockstep waves -> L1 dedups Bz
        }
    }

    // ---- bias step (p = 96): A = x row slices, B = b2 reshaped; frags in slot 0 ----
    {
        f16x2 z2 = {(f16)0.f, (f16)0.f};
        #pragma unroll
        for (int m = 0; m < 4; ++m) {
            union { f16x8 v; f16x2 q[4]; } au;
            #pragma unroll
            for (int j = 0; j < 4; ++j) {
                int i2 = quad * 4 + j;          // x feature pair index
                au.q[j] = (i2 < 12) ? xv[m][i2] : z2;
            }
            acc[m][0] = __builtin_amdgcn_mfma_f32_16x16x32_f16(au.v, pb0[0], acc[m][0], 0, 0, 0);
            acc[m][1] = __builtin_amdgcn_mfma_f32_16x16x32_f16(au.v, pb1[0], acc[m][1], 0, 0, 0);
        }
    }

    // ---- scatter: C row = quad*4+r (edge), col = l16 (+16) = o ----
    #pragma unroll
    for (int m = 0; m < 4; ++m) {
        #pragma unroll
        for (int r = 0; r < 4; ++r) {
            int er = ebase + m * 16 + quad * 4 + r;
            if (er < N_EDGES) {
                int d = dst[er];
                atomicAdd(&agg[(size_t)d * DIM + l16], acc[m][0][r]);
                if (l16 < 8) atomicAdd(&agg[(size_t)d * DIM + 16 + l16], acc[m][1][r]);
            }
        }
    }
}

// ---------- combine: x_out = [relu](agg/max(deg,1) + x_in@root + bias) ----------
__global__ void combine_kernel(
    const float* __restrict__ x_in, const float* __restrict__ agg,
    const int* __restrict__ deg, const float* __restrict__ root,
    const float* __restrict__ bias, float* __restrict__ x_out, int do_relu)
{
    int t = blockIdx.x * blockDim.x + threadIdx.x;
    if (t >= N_NODES * DIM) return;
    int v = t / DIM, o = t % DIM;
    int dg = deg[v];
    float d = dg > 0 ? (float)dg : 1.0f;
    float a = agg[t] / d + bias[o];
    const float* xr = x_in + (size_t)v * DIM;
    #pragma unroll
    for (int i = 0; i < DIM; ++i) a = fmaf(xr[i], root[i * DIM + o], a);
    x_out[t] = do_relu ? fmaxf(a, 0.0f) : a;
}

// ---------- Set2Set LSTM step: one thread per (graph, d) ----------
__global__ void lstm_kernel(
    const float* __restrict__ q_star, const float* __restrict__ h_in,
    const float* __restrict__ c_in, const float* __restrict__ w_ih,
    const float* __restrict__ w_hh, const float* __restrict__ b_ih,
    const float* __restrict__ b_hh, float* __restrict__ h_out,
    float* __restrict__ c_out)
{
    int t = blockIdx.x * blockDim.x + threadIdx.x;
    if (t >= N_GRAPHS * DIM) return;
    int g = t / DIM, d = t % DIM;
    const float* qs = q_star + (size_t)g * 48;
    const float* hv = h_in + (size_t)g * DIM;
    float gate[4];
    #pragma unroll
    for (int r4 = 0; r4 < 4; ++r4) {
        int r = r4 * DIM + d;
        float a = b_ih[r] + b_hh[r];
        const float* wi = w_ih + (size_t)r * 48;
        const float* wh = w_hh + (size_t)r * DIM;
        for (int j = 0; j < 48; ++j) a = fmaf(qs[j], wi[j], a);
        #pragma unroll
        for (int j = 0; j < DIM; ++j) a = fmaf(hv[j], wh[j], a);
        gate[r4] = a;
    }
    float c = sigm(gate[1]) * c_in[t] + sigm(gate[0]) * tanhf(gate[2]);
    h_out[t] = sigm(gate[3]) * tanhf(c);
    c_out[t] = c;
}

// ---------- per-graph attention + readout (batch sorted -> binary search) ----------
__global__ __launch_bounds__(64) void attn_kernel(
    const float* __restrict__ x, const int* __restrict__ batch,
    const float* __restrict__ h, float* __restrict__ q_star,
    float* __restrict__ e_buf)
{
    const int g = blockIdx.x;
    const int t = threadIdx.x;
    __shared__ int s_lo, s_hi;
    __shared__ float qs[DIM];
    if (t == 0) {
        int lo = 0, hi = N_NODES;
        while (lo < hi) { int m = (lo + hi) >> 1; if (batch[m] < g) lo = m + 1; else hi = m; }
        s_lo = lo;
        int lo2 = lo; hi = N_NODES;
        while (lo2 < hi) { int m = (lo2 + hi) >> 1; if (batch[m] <= g) lo2 = m + 1; else hi = m; }
        s_hi = lo2;
    }
    if (t < DIM) qs[t] = h[(size_t)g * DIM + t];
    __syncthreads();
    const int lo = s_lo, hi = s_hi;

    float mx = -INFINITY;
    for (int n = lo + t; n < hi; n += 64) {
        float xa[24];
        #pragma unroll
        for (int j = 0; j < 6; ++j)
            *(float4*)&xa[j * 4] = ((const float4*)(x + (size_t)n * DIM))[j];
        float e = 0.0f;
        #pragma unroll
        for (int d = 0; d < DIM; ++d) e = fmaf(xa[d], qs[d], e);
        e_buf[n] = e;
        mx = fmaxf(mx, e);
    }
    #pragma unroll
    for (int off = 32; off; off >>= 1) mx = fmaxf(mx, __shfl_xor(mx, off));
    float m = (hi > lo) ? mx : 0.0f;   // ref: e_max -> 0 when not finite

    float sum = 0.0f;
    for (int n = lo + t; n < hi; n += 64) sum += expf(e_buf[n] - m);
    #pragma unroll
    for (int off = 32; off; off >>= 1) sum += __shfl_xor(sum, off);
    float denom = fmaxf(sum, 1e-16f);

    float r[DIM];
    #pragma unroll
    for (int d = 0; d < DIM; ++d) r[d] = 0.0f;
    for (int n = lo + t; n < hi; n += 64) {
        float a = expf(e_buf[n] - m) / denom;
        float xa[24];
        #pragma unroll
        for (int j = 0; j < 6; ++j)
            *(float4*)&xa[j * 4] = ((const float4*)(x + (size_t)n * DIM))[j];
        #pragma unroll
        for (int d = 0; d < DIM; ++d) r[d] = fmaf(a, xa[d], r[d]);
    }
    #pragma unroll
    for (int d = 0; d < DIM; ++d) {
        #pragma unroll
        for (int off = 32; off; off >>= 1) r[d] += __shfl_xor(r[d], off);
    }
    if (t < DIM) {
        q_star[(size_t)g * 48 + t] = qs[t];       // q part
        q_star[(size_t)g * 48 + DIM + t] = r[t];  // r part
    }
}

// ---------- head: out = relu(q_star@w_fc2+b)@w_fc3+b ----------
__global__ void head_kernel(
    const float* __restrict__ q_star, const float* __restrict__ w2,
    const float* __restrict__ b2, const float* __restrict__ w3,
    const float* __restrict__ b3, float* __restrict__ out)
{
    int g = blockIdx.x * blockDim.x + threadIdx.x;
    if (g >= N_GRAPHS) return;
    const float* q = q_star + (size_t)g * 48;
    float z[8];
    #pragma unroll
    for (int k = 0; k < 8; ++k) {
        float a = b2[k];
        for (int j = 0; j < 48; ++j) a = fmaf(q[j], w2[j * 8 + k], a);
        z[k] = fmaxf(a, 0.0f);
    }
    #pragma unroll
    for (int c = 0; c < 2; ++c) {
        float a = b3[c];
        #pragma unroll
        for (int k = 0; k < 8; ++k) a = fmaf(z[k], w3[k * 2 + c], a);
        out[(size_t)g * 2 + c] = a;
    }
}

extern "C" void kernel_launch(void* const* d_in, const int* in_sizes, int n_in,
                              void* d_out, int out_size, void* d_ws, size_t ws_size,
                              hipStream_t stream) {
    const float* x      = (const float*)d_in[0];
    const float* ea     = (const float*)d_in[1];
    const float* w_e1   = (const float*)d_in[2];
    const float* b_e1   = (const float*)d_in[3];
    const float* w_e2   = (const float*)d_in[4];
    const float* b_e2   = (const float*)d_in[5];
    const float* root   = (const float*)d_in[6];
    const float* bias_c = (const float*)d_in[7];
    const float* w_ih   = (const float*)d_in[8];
    const float* w_hh   = (const float*)d_in[9];
    const float* b_ih   = (const float*)d_in[10];
    const float* b_hh   = (const float*)d_in[11];
    const float* w_fc2  = (const float*)d_in[12];
    const float* b_fc2  = (const float*)d_in[13];
    const float* w_fc3  = (const float*)d_in[14];
    const float* b_fc3  = (const float*)d_in[15];
    const int*   eidx   = (const int*)d_in[16];
    const int*   batch  = (const int*)d_in[17];
    const int* esrc = eidx;
    const int* edst = eidx + N_EDGES;
    float* out = (float*)d_out;

    // workspace layout (bytes)
    char* ws = (char*)d_ws;
    float* agg   = (float*)(ws);                  // 4,800,000
    int*   deg   = (int*)  (ws + 4800000);        //   200,000
    float* qstar = (float*)(ws + 5000000);        //   196,608
    float* h0    = (float*)(ws + 5196608);        // 4 x 98,304
    float* c0    = h0 + 24576;
    float* h1    = c0 + 24576;
    float* c1    = h1 + 24576;
    float* ebuf  = (float*)(ws + 5589824);        //   200,000
    float* x1    = (float*)(ws + 5789824);        // 4,800,000
    float* x2    = (float*)(ws + 10589824);       // 4,800,000
    f16*   Bz    = (f16*)  (ws + 15389824);       //   198,656 swizzled f16 w2+b2

    // zero: agg, deg, qstar, h0/c0/h1/c1
    hipMemsetAsync(ws, 0, 5589824, stream);

    deg_kernel<<<(N_EDGES + 255) / 256, 256, 0, stream>>>(edst, deg);
    bz_kernel<<<(97 * 2 * 64 * 8 + 255) / 256, 256, 0, stream>>>(w_e2, b_e2, Bz);

    // layer 1 (fused edge-MLP + message + scatter; no W materialization)
    conv_kernel<<<(N_EDGES + 255) / 256, 256, 0, stream>>>(x, ea, w_e1, b_e1, Bz, esrc, edst, agg);
    combine_kernel<<<(N_NODES * DIM + 255) / 256, 256, 0, stream>>>(x, agg, deg, root, bias_c, x1, 1);

    // layer 2
    hipMemsetAsync(agg, 0, 4800000, stream);
    conv_kernel<<<(N_EDGES + 255) / 256, 256, 0, stream>>>(x1, ea, w_e1, b_e1, Bz, esrc, edst, agg);
    combine_kernel<<<(N_NODES * DIM + 255) / 256, 256, 0, stream>>>(x1, agg, deg, root, bias_c, x2, 0);

    // Set2Set: 3 iterations
    float *hA = h0, *cA = c0, *hB = h1, *cB = c1;
    for (int it = 0; it < 3; ++it) {
        lstm_kernel<<<(N_GRAPHS * DIM + 255) / 256, 256, 0, stream>>>(
            qstar, hA, cA, w_ih, w_hh, b_ih, b_hh, hB, cB);
        attn_kernel<<<N_GRAPHS, 64, 0, stream>>>(x2, batch, hB, qstar, ebuf);
        float* th = hA; hA = hB; hB = th;
        float* tc = cA; cA = cB; cB = tc;
    }

    head_kernel<<<(N_GRAPHS + 255) / 256, 256, 0, stream>>>(qstar, w_fc2, b_fc2, w_fc3, b_fc3, out);
}

// Round 8
// 301.180 us; speedup vs baseline: 1.2718x; 1.2718x over previous
//
#include <hip/hip_runtime.h>
#include <math.h>

#define N_NODES 50000
#define N_EDGES 200000
#define N_GRAPHS 1024
#define DIM 24
#define EF 8
#define EH 128
#define DD 576   // 24*24
#define HSTR 136 // hs row stride in f16: 128 + 8 pad (breaks stage-A write conflicts)

typedef __attribute__((ext_vector_type(8))) _Float16 f16x8;
typedef __attribute__((ext_vector_type(4))) _Float16 f16x4;
typedef __attribute__((ext_vector_type(2))) _Float16 f16x2;
typedef __attribute__((ext_vector_type(4))) float float4e;
typedef _Float16 f16;

// ---------- helpers ----------
static __device__ __forceinline__ float sigm(float x) { return 1.0f / (1.0f + expf(-x)); }

// ---------- deg (in-degree per node) ----------
__global__ void deg_kernel(const int* __restrict__ dst, int* __restrict__ deg) {
    int i = blockIdx.x * blockDim.x + threadIdx.x;
    if (i < N_EDGES) atomicAdd(&deg[dst[i]], 1);
}

// ---------- Bz: w2 (+b2) pre-swizzled f16 into exact MFMA b-fragment order ----------
// 97 k-steps of 32: step p = si*24+i covers k-window si*32..+32 of x-feature i;
// step 96 = bias block (A = x, B = b2 reshaped).
// Layout: Bz[p 97][nt 2][lane 64][kk 8] f16; lane = quad*16+l16,
// element = B[k32=quad*8+kk][n=nt*16+l16] (n>=24 -> 0). 198,656 B, L2-resident.
__global__ __launch_bounds__(256) void bz_kernel(const float* __restrict__ w2,
                                                 const float* __restrict__ b2,
                                                 f16* __restrict__ Bz) {
    int idx = blockIdx.x * 256 + threadIdx.x;
    if (idx >= 97 * 2 * 64 * 8) return;
    int kk = idx & 7, lane = (idx >> 3) & 63, nt = (idx >> 9) & 1, p = idx >> 10;
    int q = lane >> 4, l16 = lane & 15, n = nt * 16 + l16;
    float v = 0.0f;
    if (p < 96) {
        int si = p / 24, i = p % 24;
        int k = si * 32 + q * 8 + kk;
        if (n < 24) v = w2[(size_t)k * DD + i * 24 + n];
    } else {
        int i2 = q * 8 + kk;
        if (i2 < 24 && n < 24) v = b2[i2 * 24 + n];
    }
    Bz[idx] = (f16)v;
}

// ---------- fused NNConv: h-MLP + per-edge matvec as one z-GEMM, no W ----------
// EXACT round-6 structure (measured 78us, MfmaUtil 20%): block 256 / 4 waves /
// 128 edges, wave owns 32 edges (2 m-tiles), depth-2 b-frag pipeline,
// hs[edge][k+pad], LDS 34.8KB -> 4 blocks/CU. r7's M=64 variant (2 blocks/CU)
// regressed to 102us: occupancy loss beats arithmetic-intensity gain. Frozen.
__global__ __launch_bounds__(256, 4) void conv_kernel(
    const float* __restrict__ x, const float* __restrict__ ea,
    const float* __restrict__ w1, const float* __restrict__ b1,
    const f16* __restrict__ Bz,
    const int* __restrict__ src, const int* __restrict__ dst,
    float* __restrict__ agg)
{
    __shared__ f16 hs[128 * HSTR];   // 34,816 B -> 4 blocks/CU

    const int t  = threadIdx.x;
    const int e0 = blockIdx.x * 128;

    const int lane = t & 63;
    const int wave = t >> 6;             // wave owns edges e0+wave*32 .. +32
    const int l16  = lane & 15;          // A row (edge) / B col / C col
    const int quad = lane >> 4;          // k sub-block / C row group
    const int ebase = e0 + wave * 32;

    // ---- x rows for both m-tiles -> f16 registers (issued first; L1 dedups) ----
    f16x2 xa[12], xb[12];
    {
        int ega = ebase + l16;      if (ega >= N_EDGES) ega = N_EDGES - 1;
        int egb = ebase + 16 + l16; if (egb >= N_EDGES) egb = N_EDGES - 1;
        const float* xra = x + (size_t)src[ega] * DIM;
        const float* xrb = x + (size_t)src[egb] * DIM;
        #pragma unroll
        for (int j4 = 0; j4 < 6; ++j4) {
            float4 va = *(const float4*)(xra + j4 * 4);
            float4 vb = *(const float4*)(xrb + j4 * 4);
            xa[j4 * 2]     = (f16x2){(f16)va.x, (f16)va.y};
            xa[j4 * 2 + 1] = (f16x2){(f16)va.z, (f16)va.w};
            xb[j4 * 2]     = (f16x2){(f16)vb.x, (f16)vb.y};
            xb[j4 * 2 + 1] = (f16x2){(f16)vb.z, (f16)vb.w};
        }
    }

    // ---- stage A: h = relu(ea@w1+b1) -> hs[edge][k]; thread = 4-k-slice x 16 edges ----
    {
        const int s5 = t & 31;           // k = s5*4 .. s5*4+3
        const int eb = (t >> 5) * 16;    // 16 edges starting here
        float wv[EF][4];
        #pragma unroll
        for (int j = 0; j < EF; ++j) {
            float4 v = *(const float4*)(w1 + j * EH + s5 * 4);
            wv[j][0] = v.x; wv[j][1] = v.y; wv[j][2] = v.z; wv[j][3] = v.w;
        }
        float4 bv = *(const float4*)(b1 + s5 * 4);
        const float bvv[4] = {bv.x, bv.y, bv.z, bv.w};
        #pragma unroll
        for (int e = 0; e < 16; ++e) {
            int eg = e0 + eb + e; if (eg >= N_EDGES) eg = N_EDGES - 1;  // clamp tail
            const float* ear = ea + (size_t)eg * EF;
            float4 a0 = *(const float4*)ear;
            float4 a1 = *(const float4*)(ear + 4);
            const float av[EF] = {a0.x, a0.y, a0.z, a0.w, a1.x, a1.y, a1.z, a1.w};
            float r[4] = {bvv[0], bvv[1], bvv[2], bvv[3]};
            #pragma unroll
            for (int j = 0; j < EF; ++j)
                #pragma unroll
                for (int c = 0; c < 4; ++c)
                    r[c] = fmaf(av[j], wv[j][c], r[c]);
            f16x4 hq = { (f16)fmaxf(r[0], 0.0f), (f16)fmaxf(r[1], 0.0f),
                         (f16)fmaxf(r[2], 0.0f), (f16)fmaxf(r[3], 0.0f) };
            *(f16x4*)&hs[(eb + e) * HSTR + s5 * 4] = hq;
        }
    }

    // ---- prime depth-2 b-frag pipeline (independent of LDS; overlaps barrier) ----
    const f16x8* bz = (const f16x8*)Bz + lane;
    f16x8 pb0[2], pb1[2];
    pb0[0] = bz[0];   pb1[0] = bz[64];
    pb0[1] = bz[128]; pb1[1] = bz[192];

    __syncthreads();

    float4e a00 = {0.f,0.f,0.f,0.f}, a01 = {0.f,0.f,0.f,0.f};
    float4e a10 = {0.f,0.f,0.f,0.f}, a11 = {0.f,0.f,0.f,0.f};

    #pragma unroll
    for (int si = 0; si < 4; ++si) {
        union { f16x8 v; f16x2 p[4]; } h0u, h1u;
        h0u.v = *(const f16x8*)&hs[(wave * 32 + l16) * HSTR + si * 32 + quad * 8];
        h1u.v = *(const f16x8*)&hs[(wave * 32 + 16 + l16) * HSTR + si * 32 + quad * 8];
        #pragma unroll
        for (int i = 0; i < 24; ++i) {
            const int p = si * 24 + i;          // compile-time
            f16x8 b0 = pb0[p & 1], b1v = pb1[p & 1];
            if (p + 2 <= 96) {                  // prefetch 2 steps ahead into freed slot
                pb0[p & 1] = bz[(p + 2) * 128];
                pb1[p & 1] = bz[(p + 2) * 128 + 64];
            }
            f16 xea = (i & 1) ? xa[i >> 1][1] : xa[i >> 1][0];
            f16 xeb = (i & 1) ? xb[i >> 1][1] : xb[i >> 1][0];
            f16x2 xa2 = {xea, xea}, xb2 = {xeb, xeb};
            union { f16x8 v; f16x2 p[4]; } a0u, a1u;
            #pragma unroll
            for (int j = 0; j < 4; ++j) {
                a0u.p[j] = h0u.p[j] * xa2;      // v_pk_mul_f16
                a1u.p[j] = h1u.p[j] * xb2;
            }
            a00 = __builtin_amdgcn_mfma_f32_16x16x32_f16(a0u.v, b0,  a00, 0, 0, 0);
            a10 = __builtin_amdgcn_mfma_f32_16x16x32_f16(a1u.v, b0,  a10, 0, 0, 0);
            a01 = __builtin_amdgcn_mfma_f32_16x16x32_f16(a0u.v, b1v, a01, 0, 0, 0);
            a11 = __builtin_amdgcn_mfma_f32_16x16x32_f16(a1u.v, b1v, a11, 0, 0, 0);
            if ((p % 12) == 11) __syncthreads();   // lockstep waves -> L1 dedups Bz
        }
    }

    // ---- bias step (p = 96): A = x row slices, B = b2 reshaped; frags in slot 0 ----
    {
        union { f16x8 v; f16x2 p[4]; } a0u, a1u;
        f16x2 z2 = {(f16)0.f, (f16)0.f};
        if (quad == 0)      { a0u.p[0]=xa[0]; a0u.p[1]=xa[1]; a0u.p[2]=xa[2];  a0u.p[3]=xa[3];
                              a1u.p[0]=xb[0]; a1u.p[1]=xb[1]; a1u.p[2]=xb[2];  a1u.p[3]=xb[3];  }
        else if (quad == 1) { a0u.p[0]=xa[4]; a0u.p[1]=xa[5]; a0u.p[2]=xa[6];  a0u.p[3]=xa[7];
                              a1u.p[0]=xb[4]; a1u.p[1]=xb[5]; a1u.p[2]=xb[6];  a1u.p[3]=xb[7];  }
        else if (quad == 2) { a0u.p[0]=xa[8]; a0u.p[1]=xa[9]; a0u.p[2]=xa[10]; a0u.p[3]=xa[11];
                              a1u.p[0]=xb[8]; a1u.p[1]=xb[9]; a1u.p[2]=xb[10]; a1u.p[3]=xb[11]; }
        else                { a0u.p[0]=z2; a0u.p[1]=z2; a0u.p[2]=z2; a0u.p[3]=z2;
                              a1u.p[0]=z2; a1u.p[1]=z2; a1u.p[2]=z2; a1u.p[3]=z2; }
        a00 = __builtin_amdgcn_mfma_f32_16x16x32_f16(a0u.v, pb0[0], a00, 0, 0, 0);
        a10 = __builtin_amdgcn_mfma_f32_16x16x32_f16(a1u.v, pb0[0], a10, 0, 0, 0);
        a01 = __builtin_amdgcn_mfma_f32_16x16x32_f16(a0u.v, pb1[0], a01, 0, 0, 0);
        a11 = __builtin_amdgcn_mfma_f32_16x16x32_f16(a1u.v, pb1[0], a11, 0, 0, 0);
    }

    // ---- scatter: C row = quad*4+r (edge), col = l16 (+16) = o ----
    #pragma unroll
    for (int r = 0; r < 4; ++r) {
        int er = ebase + quad * 4 + r;
        if (er < N_EDGES) {
            int d = dst[er];
            atomicAdd(&agg[(size_t)d * DIM + l16], a00[r]);
            if (l16 < 8) atomicAdd(&agg[(size_t)d * DIM + 16 + l16], a01[r]);
        }
        int er2 = ebase + 16 + quad * 4 + r;
        if (er2 < N_EDGES) {
            int d = dst[er2];
            atomicAdd(&agg[(size_t)d * DIM + l16], a10[r]);
            if (l16 < 8) atomicAdd(&agg[(size_t)d * DIM + 16 + l16], a11[r]);
        }
    }
}

// ---------- combine: x_out = [relu](agg/max(deg,1) + x_in@root + bias) ----------
__global__ void combine_kernel(
    const float* __restrict__ x_in, const float* __restrict__ agg,
    const int* __restrict__ deg, const float* __restrict__ root,
    const float* __restrict__ bias, float* __restrict__ x_out, int do_relu)
{
    int t = blockIdx.x * blockDim.x + threadIdx.x;
    if (t >= N_NODES * DIM) return;
    int v = t / DIM, o = t % DIM;
    int dg = deg[v];
    float d = dg > 0 ? (float)dg : 1.0f;
    float a = agg[t] / d + bias[o];
    const float* xr = x_in + (size_t)v * DIM;
    #pragma unroll
    for (int i = 0; i < DIM; ++i) a = fmaf(xr[i], root[i * DIM + o], a);
    x_out[t] = do_relu ? fmaxf(a, 0.0f) : a;
}

// ---------- fused Set2Set (3x LSTM+attention) + head: one block per graph ----------
// Per-graph independence: lstm[g] needs only q_star[g],h[g],c[g]; attn[g] only
// its node range. 7 dispatches + h/c/qstar/ebuf global round-trips -> 1 kernel,
// all state in LDS. Attention is single-pass online-softmax (1 x-read per
// iteration instead of 2 + e_buf write/read).
__global__ __launch_bounds__(64) void s2s_kernel(
    const float* __restrict__ x, const int* __restrict__ batch,
    const float* __restrict__ w_ih, const float* __restrict__ w_hh,
    const float* __restrict__ b_ih, const float* __restrict__ b_hh,
    const float* __restrict__ w_fc2, const float* __restrict__ b_fc2,
    const float* __restrict__ w_fc3, const float* __restrict__ b_fc3,
    float* __restrict__ out)
{
    const int g = blockIdx.x;
    const int t = threadIdx.x;     // 64 = 1 wave
    __shared__ float qs[48];       // q_star = [q | r]
    __shared__ float hh[24], cc[24], gates[96], zl[8];
    __shared__ int s_lo, s_hi;

    if (t == 0) {
        int lo = 0, hi = N_NODES;
        while (lo < hi) { int m = (lo + hi) >> 1; if (batch[m] < g) lo = m + 1; else hi = m; }
        s_lo = lo;
        int lo2 = lo; hi = N_NODES;
        while (lo2 < hi) { int m = (lo2 + hi) >> 1; if (batch[m] <= g) lo2 = m + 1; else hi = m; }
        s_hi = lo2;
    }
    if (t < 48) qs[t] = 0.0f;
    if (t < 24) { hh[t] = 0.0f; cc[t] = 0.0f; }
    __syncthreads();
    const int lo = s_lo, hi = s_hi;

    for (int it = 0; it < 3; ++it) {
        // ---- LSTM gates: rows t and 64+t (t<32); reads qs, hh ----
        for (int rr = t; rr < 96; rr += 64) {
            float a = b_ih[rr] + b_hh[rr];
            const float* wi = w_ih + (size_t)rr * 48;
            const float* wh = w_hh + (size_t)rr * 24;
            #pragma unroll
            for (int j = 0; j < 48; ++j) a = fmaf(qs[j], wi[j], a);
            #pragma unroll
            for (int j = 0; j < 24; ++j) a = fmaf(hh[j], wh[j], a);
            gates[rr] = a;
        }
        __syncthreads();
        if (t < 24) {
            float c = sigm(gates[24 + t]) * cc[t] + sigm(gates[t]) * tanhf(gates[48 + t]);
            cc[t] = c;
            float h = sigm(gates[72 + t]) * tanhf(c);
            hh[t] = h;
            qs[t] = h;               // q part of q_star
        }
        __syncthreads();

        // ---- attention: single-pass online softmax over this graph's nodes ----
        float m_l = -INFINITY, s_l = 0.0f;
        float r_l[24];
        #pragma unroll
        for (int d = 0; d < 24; ++d) r_l[d] = 0.0f;
        for (int n = lo + t; n < hi; n += 64) {
            float xv[24];
            #pragma unroll
            for (int j = 0; j < 6; ++j)
                *(float4*)&xv[j * 4] = ((const float4*)(x + (size_t)n * DIM))[j];
            float e = 0.0f;
            #pragma unroll
            for (int d = 0; d < 24; ++d) e = fmaf(xv[d], qs[d], e);
            if (e > m_l) {
                float sc = expf(m_l - e);   // exp(-inf)=0 on first node: zeros stale acc
                #pragma unroll
                for (int d = 0; d < 24; ++d) r_l[d] *= sc;
                s_l *= sc;
                m_l = e;
            }
            float w = expf(e - m_l);
            s_l += w;
            #pragma unroll
            for (int d = 0; d < 24; ++d) r_l[d] = fmaf(w, xv[d], r_l[d]);
        }
        // cross-lane merge: global max, then rescale partial sums
        float m = m_l;
        #pragma unroll
        for (int off = 32; off; off >>= 1) m = fmaxf(m, __shfl_xor(m, off));
        float fac = (m_l == -INFINITY) ? 0.0f : expf(m_l - m);
        float s = s_l * fac;
        #pragma unroll
        for (int off = 32; off; off >>= 1) s += __shfl_xor(s, off);
        float denom = fmaxf(s, 1e-16f);
        #pragma unroll
        for (int d = 0; d < 24; ++d) {
            float rv = r_l[d] * fac;
            #pragma unroll
            for (int off = 32; off; off >>= 1) rv += __shfl_xor(rv, off);
            if (t == d) qs[24 + d] = rv / denom;   // compile-time d: no scratch array
        }
        __syncthreads();
    }

    // ---- head: out = relu(q_star@w_fc2+b2)@w_fc3+b3 ----
    if (t < 8) {
        float a = b_fc2[t];
        #pragma unroll
        for (int j = 0; j < 48; ++j) a = fmaf(qs[j], w_fc2[j * 8 + t], a);
        zl[t] = fmaxf(a, 0.0f);
    }
    __syncthreads();
    if (t < 2) {
        float a = b_fc3[t];
        #pragma unroll
        for (int k = 0; k < 8; ++k) a = fmaf(zl[k], w_fc3[k * 2 + t], a);
        out[(size_t)g * 2 + t] = a;
    }
}

extern "C" void kernel_launch(void* const* d_in, const int* in_sizes, int n_in,
                              void* d_out, int out_size, void* d_ws, size_t ws_size,
                              hipStream_t stream) {
    const float* x      = (const float*)d_in[0];
    const float* ea     = (const float*)d_in[1];
    const float* w_e1   = (const float*)d_in[2];
    const float* b_e1   = (const float*)d_in[3];
    const float* w_e2   = (const float*)d_in[4];
    const float* b_e2   = (const float*)d_in[5];
    const float* root   = (const float*)d_in[6];
    const float* bias_c = (const float*)d_in[7];
    const float* w_ih   = (const float*)d_in[8];
    const float* w_hh   = (const float*)d_in[9];
    const float* b_ih   = (const float*)d_in[10];
    const float* b_hh   = (const float*)d_in[11];
    const float* w_fc2  = (const float*)d_in[12];
    const float* b_fc2  = (const float*)d_in[13];
    const float* w_fc3  = (const float*)d_in[14];
    const float* b_fc3  = (const float*)d_in[15];
    const int*   eidx   = (const int*)d_in[16];
    const int*   batch  = (const int*)d_in[17];
    const int* esrc = eidx;
    const int* edst = eidx + N_EDGES;
    float* out = (float*)d_out;

    // workspace layout (bytes)
    char* ws = (char*)d_ws;
    float* agg   = (float*)(ws);                  // 4,800,000
    int*   deg   = (int*)  (ws + 4800000);        //   200,000
    float* x1    = (float*)(ws + 5789824);        // 4,800,000
    float* x2    = (float*)(ws + 10589824);       // 4,800,000
    f16*   Bz    = (f16*)  (ws + 15389824);       //   198,656 swizzled f16 w2+b2

    // zero: agg + deg
    hipMemsetAsync(ws, 0, 5000000, stream);

    deg_kernel<<<(N_EDGES + 255) / 256, 256, 0, stream>>>(edst, deg);
    bz_kernel<<<(97 * 2 * 64 * 8 + 255) / 256, 256, 0, stream>>>(w_e2, b_e2, Bz);

    // layer 1 (fused edge-MLP + message + scatter; no W materialization)
    conv_kernel<<<(N_EDGES + 127) / 128, 256, 0, stream>>>(x, ea, w_e1, b_e1, Bz, esrc, edst, agg);
    combine_kernel<<<(N_NODES * DIM + 255) / 256, 256, 0, stream>>>(x, agg, deg, root, bias_c, x1, 1);

    // layer 2
    hipMemsetAsync(agg, 0, 4800000, stream);
    conv_kernel<<<(N_EDGES + 127) / 128, 256, 0, stream>>>(x1, ea, w_e1, b_e1, Bz, esrc, edst, agg);
    combine_kernel<<<(N_NODES * DIM + 255) / 256, 256, 0, stream>>>(x1, agg, deg, root, bias_c, x2, 0);

    // fused Set2Set (3 iterations) + head: one block per graph
    s2s_kernel<<<N_GRAPHS, 64, 0, stream>>>(x2, batch, w_ih, w_hh, b_ih, b_hh,
                                            w_fc2, b_fc2, w_fc3, b_fc3, out);
}